// Round 5
// baseline (504.096 us; speedup 1.0000x reference)
//
#include <hip/hip_runtime.h>
#include <hip/hip_bf16.h>
#include <math.h>

#define NN 50000
#define NE 800000
#define NET (NE + NN)   // edges + self loops
#define FIN 310
#define HD 128
#define NHID 64
#define NCLS 2
#define NG 128
#define NEG_SLOPE 0.2f
#define KP1 320
#define KP2 128

// dst-bucketed CSR build
#define RB 64                       // dst nodes per bucket
#define NBUK ((NN + RB - 1) / RB)   // 782
#define BCAP 2048                   // mean fill ~1087, +29 sigma safe

#define SELU_SCALE 1.0507009873554804934193349852946f
#define SELU_ALPHA 1.6732632423543772848170429916717f

typedef short bf16x8 __attribute__((ext_vector_type(8)));
typedef float f32x4 __attribute__((ext_vector_type(4)));

__device__ __forceinline__ float selu(float x) {
    return SELU_SCALE * (x > 0.f ? x : SELU_ALPHA * (expf(x) - 1.f));
}
__device__ __forceinline__ float lrelu(float x) {
    return x > 0.f ? x : NEG_SLOPE * x;
}
__device__ __forceinline__ unsigned short f2bf(float f) {
    unsigned int u = __float_as_uint(f);
    u = (u + 0x7fffu + ((u >> 16) & 1u)) >> 16;
    return (unsigned short)u;
}
__device__ __forceinline__ float bf2f(unsigned short b) {
    return __uint_as_float(((unsigned int)b) << 16);
}

// ---------------- CSR build: bucketed counting sort ----------------

// Phase A: scatter edges into dst-buckets. Bucket writes are sequential, so
// cache lines fill completely before eviction (vs 64B writeback per 4B store).
__global__ void k_bucket(const int* __restrict__ ei, int* __restrict__ bcnt,
                         unsigned int* __restrict__ buf) {
    int i = blockIdx.x * blockDim.x + threadIdx.x;
    if (i >= NET) return;
    int s, d;
    if (i < NE) { s = ei[i]; d = ei[NE + i]; }
    else        { s = i - NE; d = s; }
    int b = d >> 6;
    int pos = atomicAdd(&bcnt[b], 1);
    buf[(size_t)b * BCAP + pos] = ((unsigned int)(d & 63) << 16) | (unsigned int)s;
}

// Phase B: per-bucket LDS bin counts -> coalesced deg write.
__global__ __launch_bounds__(256) void k_bdeg(const int* __restrict__ bcnt,
                                              const unsigned int* __restrict__ buf,
                                              int* __restrict__ deg) {
    int b = blockIdx.x;
    int t = threadIdx.x;
    __shared__ int cnts[RB];
    if (t < RB) cnts[t] = 0;
    __syncthreads();
    int n = bcnt[b];
    for (int j = t; j < n; j += 256) {
        unsigned int e = buf[(size_t)b * BCAP + j];
        atomicAdd(&cnts[e >> 16], 1);
    }
    __syncthreads();
    if (t < RB) {
        int node = b * RB + t;
        if (node < NN) deg[node] = cnts[t];
    }
}

// Phase C: 3-phase scan (deg -> indptr)
__global__ __launch_bounds__(1024) void k_scan_local(const int* __restrict__ deg,
                                                     int* __restrict__ indptr,
                                                     int* __restrict__ bsum) {
    int t = threadIdx.x;
    int i = blockIdx.x * 1024 + t;
    int lane = t & 63, w = t >> 6;
    int v = (i < NN) ? deg[i] : 0;
    int x = v;
#pragma unroll
    for (int off = 1; off < 64; off <<= 1) {
        int tmp = __shfl_up(x, off);
        if (lane >= off) x += tmp;
    }
    __shared__ int wsum[16];
    if (lane == 63) wsum[w] = x;
    __syncthreads();
    if (t < 16) {
        int y = wsum[t];
#pragma unroll
        for (int off = 1; off < 16; off <<= 1) {
            int tmp = __shfl_up(y, off);
            if (t >= off) y += tmp;
        }
        wsum[t] = y;
    }
    __syncthreads();
    int incl = x + (w ? wsum[w - 1] : 0);
    if (i < NN) indptr[i] = incl - v;
    if (t == 1023) bsum[blockIdx.x] = incl;
}

__global__ __launch_bounds__(64) void k_scan_sums(int* __restrict__ bsum,
                                                  int* __restrict__ boff,
                                                  int* __restrict__ indptr, int nb) {
    int t = threadIdx.x;
    int v = (t < nb) ? bsum[t] : 0;
    int x = v;
#pragma unroll
    for (int off = 1; off < 64; off <<= 1) {
        int tmp = __shfl_up(x, off);
        if (t >= off) x += tmp;
    }
    if (t < nb) boff[t] = x - v;
    if (t == nb - 1) indptr[NN] = x;
}

__global__ __launch_bounds__(1024) void k_scan_add(int* __restrict__ indptr,
                                                   const int* __restrict__ boff) {
    int i = blockIdx.x * 1024 + threadIdx.x;
    if (i < NN) indptr[i] += boff[blockIdx.x];
}

// Phase D: per-bucket scatter into csr. Each bucket's csr range is contiguous
// (~4.3KB window) so the random writes stay on hot lines.
__global__ __launch_bounds__(256) void k_bscatter(const int* __restrict__ bcnt,
                                                  const unsigned int* __restrict__ buf,
                                                  const int* __restrict__ indptr,
                                                  int* __restrict__ csr) {
    int b = blockIdx.x;
    int t = threadIdx.x;
    __shared__ int loc[RB];
    if (t < RB) {
        int node = b * RB + t;
        loc[t] = (node < NN) ? indptr[node] : 0;
    }
    __syncthreads();
    int n = bcnt[b];
    for (int j = t; j < n; j += 256) {
        unsigned int e = buf[(size_t)b * BCAP + j];
        int pos = atomicAdd(&loc[e >> 16], 1);
        csr[pos] = (int)(e & 0xffffu);
    }
}

// ---------------- W cast + transpose (both layers, one dispatch) ----------------

__global__ void k_castT2(const float* __restrict__ W1, const float* __restrict__ W2,
                         unsigned short* __restrict__ W1t, unsigned short* __restrict__ W2t) {
    int i = blockIdx.x * blockDim.x + threadIdx.x;
    const int N1 = HD * KP1;
    if (i < N1) {
        int n = i / KP1, k = i % KP1;
        W1t[i] = (k < FIN) ? f2bf(W1[(size_t)k * HD + n]) : (unsigned short)0;
    } else {
        int j = i - N1;
        if (j < HD * KP2) {
            int n = j / KP2, k = j % KP2;
            W2t[j] = f2bf(W2[(size_t)k * HD + n]);
        }
    }
}

// ---------------- shared GEMM epilogue (C bf16 + fused dots) ----------------

#define GEMM_EPILOGUE                                                          \
    int gr_base = r0 + w * 16 + quad * 4;                                      \
    _Pragma("unroll")                                                          \
    for (int r = 0; r < 4; ++r) {                                              \
        int gr = gr_base + r;                                                  \
        if (gr < M) {                                                          \
            _Pragma("unroll")                                                  \
            for (int nt = 0; nt < 8; ++nt)                                     \
                C[(size_t)gr * HD + nt * 16 + l16] = f2bf(acc[nt][r]);         \
        }                                                                      \
    }                                                                          \
    _Pragma("unroll")                                                          \
    for (int r = 0; r < 4; ++r) {                                              \
        float s1 = 0.f, s2 = 0.f;                                              \
        _Pragma("unroll")                                                      \
        for (int nt = 0; nt < 8; ++nt) {                                       \
            int c = nt * 16 + l16;                                             \
            float v = acc[nt][r];                                              \
            s1 += v * a1s[c];                                                  \
            s2 += v * a2s[c];                                                  \
        }                                                                      \
        _Pragma("unroll")                                                      \
        for (int off = 1; off < 16; off <<= 1) {                               \
            s1 += __shfl_xor(s1, off);                                         \
            s2 += __shfl_xor(s2, off);                                         \
        }                                                                      \
        int gr = gr_base + r;                                                  \
        if (l16 == 0 && gr < M) { asrcp[gr] = s1; adstp[gr] = s2; }            \
    }

// ---- layer 1: A fp32 [M,K], K=310 (Kp=320) ----
__global__ __launch_bounds__(256) void k_gemm_f32(const float* __restrict__ A,
                                                  const unsigned short* __restrict__ Bt,
                                                  unsigned short* __restrict__ C,
                                                  float* __restrict__ asrcp,
                                                  float* __restrict__ adstp,
                                                  const float* __restrict__ a_src,
                                                  const float* __restrict__ a_dst,
                                                  int M, int K, int Kp) {
    __shared__ unsigned short As[64][40];
    __shared__ unsigned short Bs[128][40];
    __shared__ float a1s[HD], a2s[HD];
    int t = threadIdx.x;
    int lane = t & 63, w = t >> 6;
    int quad = lane >> 4, l16 = lane & 15;
    int r0 = blockIdx.x * 64;

    if (t < HD) a1s[t] = a_src[t];
    else a2s[t - HD] = a_dst[t - HD];

    f32x4 acc[8] = {};
    int arow = t >> 4;
    int acol = (t & 15) * 2;
    int brow = t >> 1;
    int bcol = (t & 1) * 16;

    for (int k0 = 0; k0 < Kp; k0 += 32) {
#pragma unroll
        for (int p = 0; p < 4; ++p) {
            int rl = arow + p * 16;
            int gr = r0 + rl;
            int gk = k0 + acol;
            float2 v = make_float2(0.f, 0.f);
            if (gr < M) {
                if (gk + 1 < K) v = *(const float2*)(A + (size_t)gr * K + gk);
                else if (gk < K) v.x = A[(size_t)gr * K + gk];
            }
            ushort2 b;
            b.x = f2bf(v.x); b.y = f2bf(v.y);
            *(ushort2*)&As[rl][acol] = b;
        }
        {
            const unsigned short* src = Bt + (size_t)brow * Kp + k0 + bcol;
            uint4 u0 = *(const uint4*)(src);
            uint4 u1 = *(const uint4*)(src + 8);
            *(uint4*)&Bs[brow][bcol] = u0;
            *(uint4*)&Bs[brow][bcol + 8] = u1;
        }
        __syncthreads();
        bf16x8 af = *(bf16x8*)&As[w * 16 + l16][quad * 8];
#pragma unroll
        for (int nt = 0; nt < 8; ++nt) {
            bf16x8 bfr = *(bf16x8*)&Bs[nt * 16 + l16][quad * 8];
            acc[nt] = __builtin_amdgcn_mfma_f32_16x16x32_bf16(af, bfr, acc[nt], 0, 0, 0);
        }
        __syncthreads();
    }
    GEMM_EPILOGUE
}

// ---- layer 2: A bf16 [M,128] ----
__global__ __launch_bounds__(256) void k_gemm_bf16(const unsigned short* __restrict__ A,
                                                   const unsigned short* __restrict__ Bt,
                                                   unsigned short* __restrict__ C,
                                                   float* __restrict__ asrcp,
                                                   float* __restrict__ adstp,
                                                   const float* __restrict__ a_src,
                                                   const float* __restrict__ a_dst,
                                                   int M, int K, int Kp) {
    __shared__ unsigned short As[64][40];
    __shared__ unsigned short Bs[128][40];
    __shared__ float a1s[HD], a2s[HD];
    int t = threadIdx.x;
    int lane = t & 63, w = t >> 6;
    int quad = lane >> 4, l16 = lane & 15;
    int r0 = blockIdx.x * 64;

    if (t < HD) a1s[t] = a_src[t];
    else a2s[t - HD] = a_dst[t - HD];

    f32x4 acc[8] = {};
    int arow = t >> 2;
    int acol = (t & 3) * 8;
    int brow = t >> 1;
    int bcol = (t & 1) * 16;

    for (int k0 = 0; k0 < Kp; k0 += 32) {
        {
            int gr = r0 + arow;
            uint4 v = make_uint4(0, 0, 0, 0);
            if (gr < M) v = *(const uint4*)(A + (size_t)gr * K + k0 + acol);
            *(uint4*)&As[arow][acol] = v;
        }
        {
            const unsigned short* src = Bt + (size_t)brow * Kp + k0 + bcol;
            uint4 u0 = *(const uint4*)(src);
            uint4 u1 = *(const uint4*)(src + 8);
            *(uint4*)&Bs[brow][bcol] = u0;
            *(uint4*)&Bs[brow][bcol + 8] = u1;
        }
        __syncthreads();
        bf16x8 af = *(bf16x8*)&As[w * 16 + l16][quad * 8];
#pragma unroll
        for (int nt = 0; nt < 8; ++nt) {
            bf16x8 bfr = *(bf16x8*)&Bs[nt * 16 + l16][quad * 8];
            acc[nt] = __builtin_amdgcn_mfma_f32_16x16x32_bf16(af, bfr, acc[nt], 0, 0, 0);
        }
        __syncthreads();
    }
    GEMM_EPILOGUE
}

// ---------------- GAT aggregation ----------------
// one wave per node; 4 groups of 16 lanes; each group handles one edge per step
// with uint4 (8 bf16) loads -> 4 edges per load instr, x4 unroll = 16 in flight.
// no softmax-max pass: exp(e)/sum(exp(e)) == softmax exactly.

__global__ __launch_bounds__(256) void k_gat(const unsigned short* __restrict__ h,
                                             const float* __restrict__ asrc,
                                             const float* __restrict__ adst,
                                             const int* __restrict__ indptr,
                                             const int* __restrict__ csr,
                                             const float* __restrict__ bias,
                                             unsigned short* __restrict__ out) {
    int node = blockIdx.x * 4 + (threadIdx.x >> 6);
    int lane = threadIdx.x & 63;
    if (node >= NN) return;
    int g = lane >> 4, cl = lane & 15;
    int start = indptr[node], end = indptr[node + 1];
    int deg = end - start;
    float adsti = adst[node];

    float acc[8] = {0.f, 0.f, 0.f, 0.f, 0.f, 0.f, 0.f, 0.f};
    float den_l = 0.f;

    for (int base = 0; base < deg; base += 64) {
        int cnt = min(64, deg - base);
        int s_c = 0; float p_c = 0.f;
        if (lane < cnt) {
            s_c = csr[start + base + lane];
            p_c = __expf(lrelu(asrc[s_c] + adsti));
        }
        den_l += p_c;
        int nt = (cnt + 3) >> 2;   // edge-quads
        for (int t = 0; t < nt; t += 4) {
            float pv[4]; uint4 hv[4];
#pragma unroll
            for (int u = 0; u < 4; ++u) {
                int tt = t + u;
                bool valid = tt < nt;
                int e = (4 * tt + g) & 63;
                int s = __shfl(s_c, e);
                float p = __shfl(p_c, e);
                int sa = valid ? s : 0;
                pv[u] = valid ? p : 0.f;
                hv[u] = *(const uint4*)(h + (size_t)sa * HD + cl * 8);
            }
#pragma unroll
            for (int u = 0; u < 4; ++u) {
                float p = pv[u];
                unsigned int w0 = hv[u].x, w1 = hv[u].y, w2 = hv[u].z, w3 = hv[u].w;
                acc[0] += p * __uint_as_float(w0 << 16);
                acc[1] += p * __uint_as_float(w0 & 0xffff0000u);
                acc[2] += p * __uint_as_float(w1 << 16);
                acc[3] += p * __uint_as_float(w1 & 0xffff0000u);
                acc[4] += p * __uint_as_float(w2 << 16);
                acc[5] += p * __uint_as_float(w2 & 0xffff0000u);
                acc[6] += p * __uint_as_float(w3 << 16);
                acc[7] += p * __uint_as_float(w3 & 0xffff0000u);
            }
        }
    }
#pragma unroll
    for (int k = 0; k < 8; ++k) {
        acc[k] += __shfl_xor(acc[k], 16);
        acc[k] += __shfl_xor(acc[k], 32);
    }
#pragma unroll
    for (int off = 32; off; off >>= 1)
        den_l += __shfl_xor(den_l, off);

    if (g == 0) {
        float inv = 1.f / den_l;
        int c0 = cl * 8;
        float4 b0 = *(const float4*)(bias + c0);
        float4 b1 = *(const float4*)(bias + c0 + 4);
        float v0 = selu(acc[0] * inv + b0.x);
        float v1 = selu(acc[1] * inv + b0.y);
        float v2 = selu(acc[2] * inv + b0.z);
        float v3 = selu(acc[3] * inv + b0.w);
        float v4 = selu(acc[4] * inv + b1.x);
        float v5 = selu(acc[5] * inv + b1.y);
        float v6 = selu(acc[6] * inv + b1.z);
        float v7 = selu(acc[7] * inv + b1.w);
        uint4 pk;
        pk.x = (unsigned int)f2bf(v0) | ((unsigned int)f2bf(v1) << 16);
        pk.y = (unsigned int)f2bf(v2) | ((unsigned int)f2bf(v3) << 16);
        pk.z = (unsigned int)f2bf(v4) | ((unsigned int)f2bf(v5) << 16);
        pk.w = (unsigned int)f2bf(v6) | ((unsigned int)f2bf(v7) << 16);
        *(uint4*)(out + (size_t)node * HD + c0) = pk;
    }
}

// ---------------- pooling + FC head (fused, one block per graph) ----------------

__device__ __forceinline__ int lower_bound_i(const int* a, int n, int key) {
    int lo = 0, hi = n;
    while (lo < hi) {
        int mid = (lo + hi) >> 1;
        if (a[mid] < key) lo = mid + 1; else hi = mid;
    }
    return lo;
}

__global__ __launch_bounds__(512) void k_poolfc(const unsigned short* __restrict__ x,
                                                const int* __restrict__ batch,
                                                const float* __restrict__ w1,
                                                const float* __restrict__ b1,
                                                const float* __restrict__ w2,
                                                const float* __restrict__ b2,
                                                float* __restrict__ out) {
    int g = blockIdx.x;
    int t = threadIdx.x;
    __shared__ int lo_s, hi_s;
    __shared__ float red[512];
    __shared__ float pooled_s[128];
    if (t == 0) {
        lo_s = lower_bound_i(batch, NN, g);
        hi_s = lower_bound_i(batch, NN, g + 1);
    }
    __syncthreads();
    int lo = lo_s, hi = hi_s;
    float acc = 0.f;
    for (int n = lo + (t >> 7); n < hi; n += 4)
        acc += bf2f(x[(size_t)n * HD + (t & 127)]);
    red[t] = acc;
    __syncthreads();
    if (t < 128) {
        float v = red[t] + red[t + 128] + red[t + 256] + red[t + 384];
        pooled_s[t] = selu(v / fmaxf((float)(hi - lo), 1.f));
    }
    __syncthreads();
    if (t < 64) {
        float z = 0.f;
#pragma unroll 8
        for (int k = 0; k < HD; ++k) z += pooled_s[k] * w1[k * NHID + t];
        z = selu(z + b1[t]);
        float p0 = z * w2[t * NCLS + 0];
        float p1 = z * w2[t * NCLS + 1];
        for (int off = 32; off; off >>= 1) {
            p0 += __shfl_down(p0, off);
            p1 += __shfl_down(p1, off);
        }
        if (t == 0) {
            float l0 = p0 + b2[0], l1 = p1 + b2[1];
            float m = fmaxf(l0, l1);
            float lse = m + logf(expf(l0 - m) + expf(l1 - m));
            out[g * NCLS + 0] = l0 - lse;
            out[g * NCLS + 1] = l1 - lse;
        }
    }
}

// ---------------- launch ----------------

static inline size_t align_up(size_t v, size_t a) { return (v + a - 1) / a * a; }

extern "C" void kernel_launch(void* const* d_in, const int* in_sizes, int n_in,
                              void* d_out, int out_size, void* d_ws, size_t ws_size,
                              hipStream_t stream) {
    const float* x      = (const float*)d_in[0];
    const int*   ei     = (const int*)d_in[1];
    const int*   batch  = (const int*)d_in[2];
    const float* W1     = (const float*)d_in[3];
    const float* a_src1 = (const float*)d_in[4];
    const float* a_dst1 = (const float*)d_in[5];
    const float* b1     = (const float*)d_in[6];
    const float* W2     = (const float*)d_in[7];
    const float* a_src2 = (const float*)d_in[8];
    const float* a_dst2 = (const float*)d_in[9];
    const float* b2     = (const float*)d_in[10];
    const float* fc1_w  = (const float*)d_in[11];
    const float* fc1_b  = (const float*)d_in[12];
    const float* fc2_w  = (const float*)d_in[13];
    const float* fc2_b  = (const float*)d_in[14];
    float* out = (float*)d_out;

    char* ws = (char*)d_ws;
    size_t off = 0;
    unsigned short* h1 = (unsigned short*)(ws + off); off = align_up(off + (size_t)NN * HD * 2, 256);
    unsigned short* o1 = (unsigned short*)(ws + off); off = align_up(off + (size_t)NN * HD * 2, 256);
    float* asrc = (float*)(ws + off); off = align_up(off + (size_t)NN * 4, 256);
    float* adst = (float*)(ws + off); off = align_up(off + (size_t)NN * 4, 256);
    int* indptr = (int*)(ws + off);   off = align_up(off + (size_t)(NN + 1) * 4, 256);
    int* deg    = (int*)(ws + off);   off = align_up(off + (size_t)NN * 4, 256);
    int* csr    = (int*)(ws + off);   off = align_up(off + (size_t)NET * 4, 256);
    unsigned int* bbuf = (unsigned int*)(ws + off); off = align_up(off + (size_t)NBUK * BCAP * 4, 256);
    int* bcnt   = (int*)(ws + off);   off = align_up(off + (size_t)NBUK * 4, 256);
    unsigned short* W1t = (unsigned short*)(ws + off); off = align_up(off + (size_t)HD * KP1 * 2, 256);
    unsigned short* W2t = (unsigned short*)(ws + off); off = align_up(off + (size_t)HD * KP2 * 2, 256);
    int* bsum = (int*)(ws + off); off = align_up(off + 64 * 4, 256);
    int* boff = (int*)(ws + off); off = align_up(off + 64 * 4, 256);
    (void)ws_size;

    const int NB = (NN + 1023) / 1024;  // 49

    // CSR build: bucketed counting sort (by dst, includes self loops)
    hipMemsetAsync(bcnt, 0, (size_t)NBUK * 4, stream);
    k_bucket<<<(NET + 255) / 256, 256, 0, stream>>>(ei, bcnt, bbuf);
    k_bdeg<<<NBUK, 256, 0, stream>>>(bcnt, bbuf, deg);
    k_scan_local<<<NB, 1024, 0, stream>>>(deg, indptr, bsum);
    k_scan_sums<<<1, 64, 0, stream>>>(bsum, boff, indptr, NB);
    k_scan_add<<<NB, 1024, 0, stream>>>(indptr, boff);
    k_bscatter<<<NBUK, 256, 0, stream>>>(bcnt, bbuf, indptr, csr);

    k_castT2<<<(HD * (KP1 + KP2) + 255) / 256, 256, 0, stream>>>(W1, W2, W1t, W2t);

    int gblocks = (NN + 63) / 64;

    // Layer 1
    k_gemm_f32<<<gblocks, 256, 0, stream>>>(x, W1t, h1, asrc, adst, a_src1, a_dst1, NN, FIN, KP1);
    k_gat<<<(NN + 3) / 4, 256, 0, stream>>>(h1, asrc, adst, indptr, csr, b1, o1);

    // Layer 2
    k_gemm_bf16<<<gblocks, 256, 0, stream>>>(o1, W2t, h1, asrc, adst, a_src2, a_dst2, NN, HD, KP2);
    k_gat<<<(NN + 3) / 4, 256, 0, stream>>>(h1, asrc, adst, indptr, csr, b2, o1);

    // Pool + FC head (fused)
    k_poolfc<<<NG, 512, 0, stream>>>(o1, batch, fc1_w, fc1_b, fc2_w, fc2_b, out);
}

// Round 6
// 315.118 us; speedup vs baseline: 1.5997x; 1.5997x over previous
//
#include <hip/hip_runtime.h>
#include <hip/hip_bf16.h>
#include <math.h>

#define NN 50000
#define NE 800000
#define NET (NE + NN)   // edges + self loops
#define FIN 310
#define HD 128
#define NHID 64
#define NCLS 2
#define NG 128
#define NEG_SLOPE 0.2f
#define KP1 320
#define KP2 128

#define SLOTS 64                    // max degree (Poisson(16)+1; P(>63) ~ 1e-22)
#define NPART 8                     // XCD count
#define PART_SZ (NN / NPART)        // 6250
#define EPB 4096                    // edges per block slice in scatter
#define NSLICE ((NET + EPB - 1) / EPB)

#define SELU_SCALE 1.0507009873554804934193349852946f
#define SELU_ALPHA 1.6732632423543772848170429916717f

typedef short bf16x8 __attribute__((ext_vector_type(8)));
typedef float f32x4 __attribute__((ext_vector_type(4)));

__device__ __forceinline__ float selu(float x) {
    return SELU_SCALE * (x > 0.f ? x : SELU_ALPHA * (expf(x) - 1.f));
}
__device__ __forceinline__ float lrelu(float x) {
    return x > 0.f ? x : NEG_SLOPE * x;
}
__device__ __forceinline__ unsigned short f2bf(float f) {
    unsigned int u = __float_as_uint(f);
    u = (u + 0x7fffu + ((u >> 16) & 1u)) >> 16;
    return (unsigned short)u;
}
__device__ __forceinline__ float bf2f(unsigned short b) {
    return __uint_as_float(((unsigned int)b) << 16);
}

// ---------------- adjacency build: direct slotted scatter ----------------
// part = blockIdx & 7 -> XCD round-robin heuristic: each dst range is written
// by one XCD only, so slot cache lines fill completely in that XCD's L2
// (fixes the 55MB partial-line writeback of a global random scatter).
// Cost: NPART x re-read of the edge list (~54MB ~ 9us).

__global__ __launch_bounds__(256) void k_scatter_slots(const int* __restrict__ ei,
                                                       int* __restrict__ cursor,
                                                       int* __restrict__ slots) {
    int part = blockIdx.x & (NPART - 1);
    int slice = blockIdx.x >> 3;
    int lo = part * PART_SZ;
    int base = slice * EPB + threadIdx.x;
#pragma unroll
    for (int k = 0; k < EPB / 256; ++k) {
        int i = base + k * 256;
        if (i >= NET) break;
        int d = (i < NE) ? ei[NE + i] : (i - NE);
        if ((unsigned)(d - lo) < (unsigned)PART_SZ) {
            int s = (i < NE) ? ei[i] : d;
            int pos = atomicAdd(&cursor[d], 1) & (SLOTS - 1);
            slots[(size_t)d * SLOTS + pos] = s;
        }
    }
}

// ---------------- W cast + transpose (both layers, one dispatch) ----------------

__global__ void k_castT2(const float* __restrict__ W1, const float* __restrict__ W2,
                         unsigned short* __restrict__ W1t, unsigned short* __restrict__ W2t) {
    int i = blockIdx.x * blockDim.x + threadIdx.x;
    const int N1 = HD * KP1;
    if (i < N1) {
        int n = i / KP1, k = i % KP1;
        W1t[i] = (k < FIN) ? f2bf(W1[(size_t)k * HD + n]) : (unsigned short)0;
    } else {
        int j = i - N1;
        if (j < HD * KP2) {
            int n = j / KP2, k = j % KP2;
            W2t[j] = f2bf(W2[(size_t)k * HD + n]);
        }
    }
}

// ---------------- shared GEMM epilogue (C bf16 + fused dots) ----------------

#define GEMM_EPILOGUE                                                          \
    int gr_base = r0 + w * 16 + quad * 4;                                      \
    _Pragma("unroll")                                                          \
    for (int r = 0; r < 4; ++r) {                                              \
        int gr = gr_base + r;                                                  \
        if (gr < M) {                                                          \
            _Pragma("unroll")                                                  \
            for (int nt = 0; nt < 8; ++nt)                                     \
                C[(size_t)gr * HD + nt * 16 + l16] = f2bf(acc[nt][r]);         \
        }                                                                      \
    }                                                                          \
    _Pragma("unroll")                                                          \
    for (int r = 0; r < 4; ++r) {                                              \
        float s1 = 0.f, s2 = 0.f;                                              \
        _Pragma("unroll")                                                      \
        for (int nt = 0; nt < 8; ++nt) {                                       \
            int c = nt * 16 + l16;                                             \
            float v = acc[nt][r];                                              \
            s1 += v * a1s[c];                                                  \
            s2 += v * a2s[c];                                                  \
        }                                                                      \
        _Pragma("unroll")                                                      \
        for (int off = 1; off < 16; off <<= 1) {                               \
            s1 += __shfl_xor(s1, off);                                         \
            s2 += __shfl_xor(s2, off);                                         \
        }                                                                      \
        int gr = gr_base + r;                                                  \
        if (l16 == 0 && gr < M) { asrcp[gr] = s1; adstp[gr] = s2; }            \
    }

// ---- layer 1: A fp32 [M,K], K=310 (Kp=320) ----
__global__ __launch_bounds__(256) void k_gemm_f32(const float* __restrict__ A,
                                                  const unsigned short* __restrict__ Bt,
                                                  unsigned short* __restrict__ C,
                                                  float* __restrict__ asrcp,
                                                  float* __restrict__ adstp,
                                                  const float* __restrict__ a_src,
                                                  const float* __restrict__ a_dst,
                                                  int M, int K, int Kp) {
    __shared__ unsigned short As[64][40];
    __shared__ unsigned short Bs[128][40];
    __shared__ float a1s[HD], a2s[HD];
    int t = threadIdx.x;
    int lane = t & 63, w = t >> 6;
    int quad = lane >> 4, l16 = lane & 15;
    int r0 = blockIdx.x * 64;

    if (t < HD) a1s[t] = a_src[t];
    else a2s[t - HD] = a_dst[t - HD];

    f32x4 acc[8] = {};
    int arow = t >> 4;
    int acol = (t & 15) * 2;
    int brow = t >> 1;
    int bcol = (t & 1) * 16;

    for (int k0 = 0; k0 < Kp; k0 += 32) {
#pragma unroll
        for (int p = 0; p < 4; ++p) {
            int rl = arow + p * 16;
            int gr = r0 + rl;
            int gk = k0 + acol;
            float2 v = make_float2(0.f, 0.f);
            if (gr < M) {
                if (gk + 1 < K) v = *(const float2*)(A + (size_t)gr * K + gk);
                else if (gk < K) v.x = A[(size_t)gr * K + gk];
            }
            ushort2 b;
            b.x = f2bf(v.x); b.y = f2bf(v.y);
            *(ushort2*)&As[rl][acol] = b;
        }
        {
            const unsigned short* src = Bt + (size_t)brow * Kp + k0 + bcol;
            uint4 u0 = *(const uint4*)(src);
            uint4 u1 = *(const uint4*)(src + 8);
            *(uint4*)&Bs[brow][bcol] = u0;
            *(uint4*)&Bs[brow][bcol + 8] = u1;
        }
        __syncthreads();
        bf16x8 af = *(bf16x8*)&As[w * 16 + l16][quad * 8];
#pragma unroll
        for (int nt = 0; nt < 8; ++nt) {
            bf16x8 bfr = *(bf16x8*)&Bs[nt * 16 + l16][quad * 8];
            acc[nt] = __builtin_amdgcn_mfma_f32_16x16x32_bf16(af, bfr, acc[nt], 0, 0, 0);
        }
        __syncthreads();
    }
    GEMM_EPILOGUE
}

// ---- layer 2: A bf16 [M,128] ----
__global__ __launch_bounds__(256) void k_gemm_bf16(const unsigned short* __restrict__ A,
                                                   const unsigned short* __restrict__ Bt,
                                                   unsigned short* __restrict__ C,
                                                   float* __restrict__ asrcp,
                                                   float* __restrict__ adstp,
                                                   const float* __restrict__ a_src,
                                                   const float* __restrict__ a_dst,
                                                   int M, int K, int Kp) {
    __shared__ unsigned short As[64][40];
    __shared__ unsigned short Bs[128][40];
    __shared__ float a1s[HD], a2s[HD];
    int t = threadIdx.x;
    int lane = t & 63, w = t >> 6;
    int quad = lane >> 4, l16 = lane & 15;
    int r0 = blockIdx.x * 64;

    if (t < HD) a1s[t] = a_src[t];
    else a2s[t - HD] = a_dst[t - HD];

    f32x4 acc[8] = {};
    int arow = t >> 2;
    int acol = (t & 3) * 8;
    int brow = t >> 1;
    int bcol = (t & 1) * 16;

    for (int k0 = 0; k0 < Kp; k0 += 32) {
        {
            int gr = r0 + arow;
            uint4 v = make_uint4(0, 0, 0, 0);
            if (gr < M) v = *(const uint4*)(A + (size_t)gr * K + k0 + acol);
            *(uint4*)&As[arow][acol] = v;
        }
        {
            const unsigned short* src = Bt + (size_t)brow * Kp + k0 + bcol;
            uint4 u0 = *(const uint4*)(src);
            uint4 u1 = *(const uint4*)(src + 8);
            *(uint4*)&Bs[brow][bcol] = u0;
            *(uint4*)&Bs[brow][bcol + 8] = u1;
        }
        __syncthreads();
        bf16x8 af = *(bf16x8*)&As[w * 16 + l16][quad * 8];
#pragma unroll
        for (int nt = 0; nt < 8; ++nt) {
            bf16x8 bfr = *(bf16x8*)&Bs[nt * 16 + l16][quad * 8];
            acc[nt] = __builtin_amdgcn_mfma_f32_16x16x32_bf16(af, bfr, acc[nt], 0, 0, 0);
        }
        __syncthreads();
    }
    GEMM_EPILOGUE
}

// ---------------- GAT aggregation ----------------
// one wave per node; deg <= 64 so a single 64-edge chunk. 4 groups of 16 lanes,
// uint4 (8 bf16) row loads -> 4 edges per instr, x4 unroll = 16 in flight.
// exp(e)/sum(exp(e)) == softmax exactly (no max pass needed).

__global__ __launch_bounds__(256) void k_gat(const unsigned short* __restrict__ h,
                                             const float* __restrict__ asrc,
                                             const float* __restrict__ adst,
                                             const int* __restrict__ degv,
                                             const int* __restrict__ slots,
                                             const float* __restrict__ bias,
                                             unsigned short* __restrict__ out) {
    int node = blockIdx.x * 4 + (threadIdx.x >> 6);
    int lane = threadIdx.x & 63;
    if (node >= NN) return;
    int g = lane >> 4, cl = lane & 15;
    int deg = degv[node];
    float adsti = adst[node];

    float acc[8] = {0.f, 0.f, 0.f, 0.f, 0.f, 0.f, 0.f, 0.f};

    int cnt = min(deg, SLOTS);
    int s_c = 0; float p_c = 0.f;
    if (lane < cnt) {
        s_c = slots[(size_t)node * SLOTS + lane];
        p_c = __expf(lrelu(asrc[s_c] + adsti));
    }
    float den_l = p_c;
    int nt = (cnt + 3) >> 2;   // edge-quads
    for (int t = 0; t < nt; t += 4) {
        float pv[4]; uint4 hv[4];
#pragma unroll
        for (int u = 0; u < 4; ++u) {
            int tt = t + u;
            bool valid = tt < nt;
            int e = (4 * tt + g) & 63;
            int s = __shfl(s_c, e);
            float p = __shfl(p_c, e);
            int sa = valid ? s : 0;
            pv[u] = valid ? p : 0.f;
            hv[u] = *(const uint4*)(h + (size_t)sa * HD + cl * 8);
        }
#pragma unroll
        for (int u = 0; u < 4; ++u) {
            float p = pv[u];
            unsigned int w0 = hv[u].x, w1 = hv[u].y, w2 = hv[u].z, w3 = hv[u].w;
            acc[0] += p * __uint_as_float(w0 << 16);
            acc[1] += p * __uint_as_float(w0 & 0xffff0000u);
            acc[2] += p * __uint_as_float(w1 << 16);
            acc[3] += p * __uint_as_float(w1 & 0xffff0000u);
            acc[4] += p * __uint_as_float(w2 << 16);
            acc[5] += p * __uint_as_float(w2 & 0xffff0000u);
            acc[6] += p * __uint_as_float(w3 << 16);
            acc[7] += p * __uint_as_float(w3 & 0xffff0000u);
        }
    }
#pragma unroll
    for (int k = 0; k < 8; ++k) {
        acc[k] += __shfl_xor(acc[k], 16);
        acc[k] += __shfl_xor(acc[k], 32);
    }
#pragma unroll
    for (int off = 32; off; off >>= 1)
        den_l += __shfl_xor(den_l, off);

    if (g == 0) {
        float inv = 1.f / den_l;
        int c0 = cl * 8;
        float4 b0 = *(const float4*)(bias + c0);
        float4 b1 = *(const float4*)(bias + c0 + 4);
        float v0 = selu(acc[0] * inv + b0.x);
        float v1 = selu(acc[1] * inv + b0.y);
        float v2 = selu(acc[2] * inv + b0.z);
        float v3 = selu(acc[3] * inv + b0.w);
        float v4 = selu(acc[4] * inv + b1.x);
        float v5 = selu(acc[5] * inv + b1.y);
        float v6 = selu(acc[6] * inv + b1.z);
        float v7 = selu(acc[7] * inv + b1.w);
        uint4 pk;
        pk.x = (unsigned int)f2bf(v0) | ((unsigned int)f2bf(v1) << 16);
        pk.y = (unsigned int)f2bf(v2) | ((unsigned int)f2bf(v3) << 16);
        pk.z = (unsigned int)f2bf(v4) | ((unsigned int)f2bf(v5) << 16);
        pk.w = (unsigned int)f2bf(v6) | ((unsigned int)f2bf(v7) << 16);
        *(uint4*)(out + (size_t)node * HD + c0) = pk;
    }
}

// ---------------- pooling + FC head (fused, one block per graph) ----------------

__device__ __forceinline__ int lower_bound_i(const int* a, int n, int key) {
    int lo = 0, hi = n;
    while (lo < hi) {
        int mid = (lo + hi) >> 1;
        if (a[mid] < key) lo = mid + 1; else hi = mid;
    }
    return lo;
}

__global__ __launch_bounds__(512) void k_poolfc(const unsigned short* __restrict__ x,
                                                const int* __restrict__ batch,
                                                const float* __restrict__ w1,
                                                const float* __restrict__ b1,
                                                const float* __restrict__ w2,
                                                const float* __restrict__ b2,
                                                float* __restrict__ out) {
    int g = blockIdx.x;
    int t = threadIdx.x;
    __shared__ int lo_s, hi_s;
    __shared__ float red[512];
    __shared__ float pooled_s[128];
    if (t == 0) {
        lo_s = lower_bound_i(batch, NN, g);
        hi_s = lower_bound_i(batch, NN, g + 1);
    }
    __syncthreads();
    int lo = lo_s, hi = hi_s;
    float acc = 0.f;
    for (int n = lo + (t >> 7); n < hi; n += 4)
        acc += bf2f(x[(size_t)n * HD + (t & 127)]);
    red[t] = acc;
    __syncthreads();
    if (t < 128) {
        float v = red[t] + red[t + 128] + red[t + 256] + red[t + 384];
        pooled_s[t] = selu(v / fmaxf((float)(hi - lo), 1.f));
    }
    __syncthreads();
    if (t < 64) {
        float z = 0.f;
#pragma unroll 8
        for (int k = 0; k < HD; ++k) z += pooled_s[k] * w1[k * NHID + t];
        z = selu(z + b1[t]);
        float p0 = z * w2[t * NCLS + 0];
        float p1 = z * w2[t * NCLS + 1];
        for (int off = 32; off; off >>= 1) {
            p0 += __shfl_down(p0, off);
            p1 += __shfl_down(p1, off);
        }
        if (t == 0) {
            float l0 = p0 + b2[0], l1 = p1 + b2[1];
            float m = fmaxf(l0, l1);
            float lse = m + logf(expf(l0 - m) + expf(l1 - m));
            out[g * NCLS + 0] = l0 - lse;
            out[g * NCLS + 1] = l1 - lse;
        }
    }
}

// ---------------- launch ----------------

static inline size_t align_up(size_t v, size_t a) { return (v + a - 1) / a * a; }

extern "C" void kernel_launch(void* const* d_in, const int* in_sizes, int n_in,
                              void* d_out, int out_size, void* d_ws, size_t ws_size,
                              hipStream_t stream) {
    const float* x      = (const float*)d_in[0];
    const int*   ei     = (const int*)d_in[1];
    const int*   batch  = (const int*)d_in[2];
    const float* W1     = (const float*)d_in[3];
    const float* a_src1 = (const float*)d_in[4];
    const float* a_dst1 = (const float*)d_in[5];
    const float* b1     = (const float*)d_in[6];
    const float* W2     = (const float*)d_in[7];
    const float* a_src2 = (const float*)d_in[8];
    const float* a_dst2 = (const float*)d_in[9];
    const float* b2     = (const float*)d_in[10];
    const float* fc1_w  = (const float*)d_in[11];
    const float* fc1_b  = (const float*)d_in[12];
    const float* fc2_w  = (const float*)d_in[13];
    const float* fc2_b  = (const float*)d_in[14];
    float* out = (float*)d_out;

    char* ws = (char*)d_ws;
    size_t off = 0;
    unsigned short* h1 = (unsigned short*)(ws + off); off = align_up(off + (size_t)NN * HD * 2, 256);
    unsigned short* o1 = (unsigned short*)(ws + off); off = align_up(off + (size_t)NN * HD * 2, 256);
    float* asrc = (float*)(ws + off); off = align_up(off + (size_t)NN * 4, 256);
    float* adst = (float*)(ws + off); off = align_up(off + (size_t)NN * 4, 256);
    int* cursor = (int*)(ws + off);   off = align_up(off + (size_t)NN * 4, 256);
    int* slots  = (int*)(ws + off);   off = align_up(off + (size_t)NN * SLOTS * 4, 256);
    unsigned short* W1t = (unsigned short*)(ws + off); off = align_up(off + (size_t)HD * KP1 * 2, 256);
    unsigned short* W2t = (unsigned short*)(ws + off); off = align_up(off + (size_t)HD * KP2 * 2, 256);
    (void)ws_size;

    // adjacency build: slotted scatter, XCD-partitioned by dst range
    hipMemsetAsync(cursor, 0, (size_t)NN * 4, stream);
    k_scatter_slots<<<NSLICE * NPART, 256, 0, stream>>>(ei, cursor, slots);

    k_castT2<<<(HD * (KP1 + KP2) + 255) / 256, 256, 0, stream>>>(W1, W2, W1t, W2t);

    int gblocks = (NN + 63) / 64;

    // Layer 1
    k_gemm_f32<<<gblocks, 256, 0, stream>>>(x, W1t, h1, asrc, adst, a_src1, a_dst1, NN, FIN, KP1);
    k_gat<<<(NN + 3) / 4, 256, 0, stream>>>(h1, asrc, adst, cursor, slots, b1, o1);

    // Layer 2
    k_gemm_bf16<<<gblocks, 256, 0, stream>>>(o1, W2t, h1, asrc, adst, a_src2, a_dst2, NN, HD, KP2);
    k_gat<<<(NN + 3) / 4, 256, 0, stream>>>(h1, asrc, adst, cursor, slots, b2, o1);

    // Pool + FC head (fused)
    k_poolfc<<<NG, 512, 0, stream>>>(o1, batch, fc1_w, fc1_b, fc2_w, fc2_b, out);
}

// Round 7
// 309.133 us; speedup vs baseline: 1.6307x; 1.0194x over previous
//
#include <hip/hip_runtime.h>
#include <hip/hip_bf16.h>
#include <math.h>

#define NN 50000
#define NE 800000
#define NET (NE + NN)   // edges + self loops
#define FIN 310
#define HD 128
#define NHID 64
#define NCLS 2
#define NG 128
#define NEG_SLOPE 0.2f
#define KP1 320
#define KP2 128

#define SLOTS 64                    // max degree (Poisson(16)+1; P(>63) ~ 1e-22)
#define NPART 8                     // XCD count
#define PART_SZ (NN / NPART)        // 6250
#define EPB 4096
#define NSLICE ((NET + EPB - 1) / EPB)

#define SELU_SCALE 1.0507009873554804934193349852946f
#define SELU_ALPHA 1.6732632423543772848170429916717f

typedef short bf16x8 __attribute__((ext_vector_type(8)));
typedef float f32x4 __attribute__((ext_vector_type(4)));

__device__ __forceinline__ float selu(float x) {
    return SELU_SCALE * (x > 0.f ? x : SELU_ALPHA * (__expf(x) - 1.f));
}
__device__ __forceinline__ float lrelu(float x) {
    return x > 0.f ? x : NEG_SLOPE * x;
}
__device__ __forceinline__ unsigned short f2bf(float f) {
    unsigned int u = __float_as_uint(f);
    u = (u + 0x7fffu + ((u >> 16) & 1u)) >> 16;
    return (unsigned short)u;
}
__device__ __forceinline__ float bf2f(unsigned short b) {
    return __uint_as_float(((unsigned int)b) << 16);
}

// ---------------- adjacency build: direct slotted scatter ----------------
// part = blockIdx & 7 -> XCD round-robin: each dst range is written by one
// XCD only, so slot cache lines fill completely in that XCD's L2.

__global__ __launch_bounds__(256) void k_scatter_slots(const int* __restrict__ ei,
                                                       int* __restrict__ cursor,
                                                       int* __restrict__ slots) {
    int part = blockIdx.x & (NPART - 1);
    int slice = blockIdx.x >> 3;
    int lo = part * PART_SZ;
    int base = slice * EPB + threadIdx.x;
#pragma unroll
    for (int k = 0; k < EPB / 256; ++k) {
        int i = base + k * 256;
        if (i >= NET) break;
        int d = (i < NE) ? ei[NE + i] : (i - NE);
        if ((unsigned)(d - lo) < (unsigned)PART_SZ) {
            int s = (i < NE) ? ei[i] : d;
            int pos = atomicAdd(&cursor[d], 1) & (SLOTS - 1);
            slots[(size_t)d * SLOTS + pos] = s;
        }
    }
}

// ---------------- W cast + transpose (both layers, one dispatch) ----------------

__global__ void k_castT2(const float* __restrict__ W1, const float* __restrict__ W2,
                         unsigned short* __restrict__ W1t, unsigned short* __restrict__ W2t) {
    int i = blockIdx.x * blockDim.x + threadIdx.x;
    const int N1 = HD * KP1;
    if (i < N1) {
        int n = i / KP1, k = i % KP1;
        W1t[i] = (k < FIN) ? f2bf(W1[(size_t)k * HD + n]) : (unsigned short)0;
    } else {
        int j = i - N1;
        if (j < HD * KP2) {
            int n = j / KP2, k = j % KP2;
            W2t[j] = f2bf(W2[(size_t)k * HD + n]);
        }
    }
}

// ---------------- GEMM: 32-row tiles, 4 waves, fused attention dots -----------
// wave w: row-half rh=w&1 (16 rows), col-half ch=w>>1 (64 cols), acc 4x f32x4.
// Fused dots are per-wave partial (64 cols) -> combined via LDS.

#define GEMM_EPILOGUE                                                          \
    int rh = w & 1, chf = w >> 1;                                              \
    int gr_base = r0 + rh * 16 + quad * 4;                                     \
    _Pragma("unroll")                                                          \
    for (int r = 0; r < 4; ++r) {                                              \
        int gr = gr_base + r;                                                  \
        if (gr < M) {                                                          \
            _Pragma("unroll")                                                  \
            for (int nt = 0; nt < 4; ++nt)                                     \
                C[(size_t)gr * HD + chf * 64 + nt * 16 + l16] = f2bf(acc[nt][r]); \
        }                                                                      \
    }                                                                          \
    _Pragma("unroll")                                                          \
    for (int r = 0; r < 4; ++r) {                                              \
        float s1 = 0.f, s2 = 0.f;                                              \
        _Pragma("unroll")                                                      \
        for (int nt = 0; nt < 4; ++nt) {                                       \
            int c = chf * 64 + nt * 16 + l16;                                  \
            float v = acc[nt][r];                                              \
            s1 += v * a1s[c];                                                  \
            s2 += v * a2s[c];                                                  \
        }                                                                      \
        _Pragma("unroll")                                                      \
        for (int off = 1; off < 16; off <<= 1) {                               \
            s1 += __shfl_xor(s1, off);                                         \
            s2 += __shfl_xor(s2, off);                                         \
        }                                                                      \
        if (l16 == 0) {                                                        \
            pd[0][rh][chf][quad * 4 + r] = s1;                                 \
            pd[1][rh][chf][quad * 4 + r] = s2;                                 \
        }                                                                      \
    }                                                                          \
    __syncthreads();                                                           \
    if (t < 64) {                                                              \
        int idx = t & 15;                                                      \
        int rh2 = (t >> 4) & 1;                                                \
        int which = t >> 5;                                                    \
        float val = pd[which][rh2][0][idx] + pd[which][rh2][1][idx];           \
        int gr = r0 + rh2 * 16 + idx;                                          \
        if (gr < M) { if (which) adstp[gr] = val; else asrcp[gr] = val; }      \
    }

// ---- layer 1: A fp32 [M,K], K=310 (Kp=320) ----
__global__ __launch_bounds__(256) void k_gemm_f32(const float* __restrict__ A,
                                                  const unsigned short* __restrict__ Bt,
                                                  unsigned short* __restrict__ C,
                                                  float* __restrict__ asrcp,
                                                  float* __restrict__ adstp,
                                                  const float* __restrict__ a_src,
                                                  const float* __restrict__ a_dst,
                                                  int M, int K, int Kp) {
    __shared__ unsigned short As[32][40];
    __shared__ unsigned short Bs[128][40];
    __shared__ float a1s[HD], a2s[HD];
    __shared__ float pd[2][2][2][16];
    int t = threadIdx.x;
    int lane = t & 63, w = t >> 6;
    int quad = lane >> 4, l16 = lane & 15;
    int r0 = blockIdx.x * 32;

    if (t < HD) a1s[t] = a_src[t];
    else a2s[t - HD] = a_dst[t - HD];

    f32x4 acc[4] = {};
    int arow = t >> 4;          // 0..15 (+16*pass)
    int acol = (t & 15) * 2;
    int brow = t >> 1;
    int bcol = (t & 1) * 16;

    for (int k0 = 0; k0 < Kp; k0 += 32) {
#pragma unroll
        for (int p = 0; p < 2; ++p) {
            int rl = arow + p * 16;
            int gr = r0 + rl;
            int gk = k0 + acol;
            float2 v = make_float2(0.f, 0.f);
            if (gr < M) {
                if (gk + 1 < K) v = *(const float2*)(A + (size_t)gr * K + gk);
                else if (gk < K) v.x = A[(size_t)gr * K + gk];
            }
            ushort2 b;
            b.x = f2bf(v.x); b.y = f2bf(v.y);
            *(ushort2*)&As[rl][acol] = b;
        }
        {
            const unsigned short* src = Bt + (size_t)brow * Kp + k0 + bcol;
            uint4 u0 = *(const uint4*)(src);
            uint4 u1 = *(const uint4*)(src + 8);
            *(uint4*)&Bs[brow][bcol] = u0;
            *(uint4*)&Bs[brow][bcol + 8] = u1;
        }
        __syncthreads();
        bf16x8 af = *(bf16x8*)&As[(w & 1) * 16 + l16][quad * 8];
#pragma unroll
        for (int nt = 0; nt < 4; ++nt) {
            bf16x8 bfr = *(bf16x8*)&Bs[(w >> 1) * 64 + nt * 16 + l16][quad * 8];
            acc[nt] = __builtin_amdgcn_mfma_f32_16x16x32_bf16(af, bfr, acc[nt], 0, 0, 0);
        }
        __syncthreads();
    }
    GEMM_EPILOGUE
}

// ---- layer 2: A bf16 [M,128] ----
__global__ __launch_bounds__(256) void k_gemm_bf16(const unsigned short* __restrict__ A,
                                                   const unsigned short* __restrict__ Bt,
                                                   unsigned short* __restrict__ C,
                                                   float* __restrict__ asrcp,
                                                   float* __restrict__ adstp,
                                                   const float* __restrict__ a_src,
                                                   const float* __restrict__ a_dst,
                                                   int M, int K, int Kp) {
    __shared__ unsigned short As[32][40];
    __shared__ unsigned short Bs[128][40];
    __shared__ float a1s[HD], a2s[HD];
    __shared__ float pd[2][2][2][16];
    int t = threadIdx.x;
    int lane = t & 63, w = t >> 6;
    int quad = lane >> 4, l16 = lane & 15;
    int r0 = blockIdx.x * 32;

    if (t < HD) a1s[t] = a_src[t];
    else a2s[t - HD] = a_dst[t - HD];

    f32x4 acc[4] = {};
    int arow = t >> 3;          // 0..31
    int acol = (t & 7) * 4;     // 0,4,..,28
    int brow = t >> 1;
    int bcol = (t & 1) * 16;

    for (int k0 = 0; k0 < Kp; k0 += 32) {
        {
            int gr = r0 + arow;
            uint2 v = make_uint2(0, 0);
            if (gr < M) v = *(const uint2*)(A + (size_t)gr * K + k0 + acol);
            *(uint2*)&As[arow][acol] = v;
        }
        {
            const unsigned short* src = Bt + (size_t)brow * Kp + k0 + bcol;
            uint4 u0 = *(const uint4*)(src);
            uint4 u1 = *(const uint4*)(src + 8);
            *(uint4*)&Bs[brow][bcol] = u0;
            *(uint4*)&Bs[brow][bcol + 8] = u1;
        }
        __syncthreads();
        bf16x8 af = *(bf16x8*)&As[(w & 1) * 16 + l16][quad * 8];
#pragma unroll
        for (int nt = 0; nt < 4; ++nt) {
            bf16x8 bfr = *(bf16x8*)&Bs[(w >> 1) * 64 + nt * 16 + l16][quad * 8];
            acc[nt] = __builtin_amdgcn_mfma_f32_16x16x32_bf16(af, bfr, acc[nt], 0, 0, 0);
        }
        __syncthreads();
    }
    GEMM_EPILOGUE
}

// ---------------- GAT aggregation ----------------
// one wave per node; 4 groups of 16 lanes, uint4 (8 bf16) row loads -> 4 edges
// per instr, x2 unroll (8 in flight; mean deg=17 so x4 wasted 40% of slots).
// float2 accumulators -> v_pk_fma_f32. exp/sum(exp) == softmax exactly.

__global__ __launch_bounds__(256) void k_gat(const unsigned short* __restrict__ h,
                                             const float* __restrict__ asrc,
                                             const float* __restrict__ adst,
                                             const int* __restrict__ degv,
                                             const int* __restrict__ slots,
                                             const float* __restrict__ bias,
                                             unsigned short* __restrict__ out) {
    int node = blockIdx.x * 4 + (threadIdx.x >> 6);
    int lane = threadIdx.x & 63;
    if (node >= NN) return;
    int g = lane >> 4, cl = lane & 15;
    int deg = degv[node];
    float adsti = adst[node];

    float2 acc2[4] = {};

    int cnt = min(deg, SLOTS);
    int s_c = 0; float p_c = 0.f;
    if (lane < cnt) {
        s_c = slots[(size_t)node * SLOTS + lane];
        p_c = __expf(lrelu(asrc[s_c] + adsti));
    }
    float den_l = p_c;
    int nt = (cnt + 3) >> 2;   // edge-quads
    for (int t = 0; t < nt; t += 2) {
        float pv[2]; uint4 hv[2];
#pragma unroll
        for (int u = 0; u < 2; ++u) {
            int tt = t + u;
            bool valid = tt < nt;
            int e = (4 * tt + g) & 63;
            int s = __shfl(s_c, e);
            float p = __shfl(p_c, e);
            int sa = valid ? s : 0;
            pv[u] = valid ? p : 0.f;
            hv[u] = *(const uint4*)(h + (size_t)sa * HD + cl * 8);
        }
#pragma unroll
        for (int u = 0; u < 2; ++u) {
            float p = pv[u];
            unsigned int w0 = hv[u].x, w1 = hv[u].y, w2 = hv[u].z, w3 = hv[u].w;
            acc2[0].x += p * __uint_as_float(w0 << 16);
            acc2[0].y += p * __uint_as_float(w0 & 0xffff0000u);
            acc2[1].x += p * __uint_as_float(w1 << 16);
            acc2[1].y += p * __uint_as_float(w1 & 0xffff0000u);
            acc2[2].x += p * __uint_as_float(w2 << 16);
            acc2[2].y += p * __uint_as_float(w2 & 0xffff0000u);
            acc2[3].x += p * __uint_as_float(w3 << 16);
            acc2[3].y += p * __uint_as_float(w3 & 0xffff0000u);
        }
    }
#pragma unroll
    for (int k = 0; k < 4; ++k) {
        acc2[k].x += __shfl_xor(acc2[k].x, 16);
        acc2[k].y += __shfl_xor(acc2[k].y, 16);
        acc2[k].x += __shfl_xor(acc2[k].x, 32);
        acc2[k].y += __shfl_xor(acc2[k].y, 32);
    }
#pragma unroll
    for (int off = 32; off; off >>= 1)
        den_l += __shfl_xor(den_l, off);

    if (g == 0) {
        float inv = 1.f / den_l;
        int c0 = cl * 8;
        float4 b0 = *(const float4*)(bias + c0);
        float4 b1 = *(const float4*)(bias + c0 + 4);
        float v0 = selu(acc2[0].x * inv + b0.x);
        float v1 = selu(acc2[0].y * inv + b0.y);
        float v2 = selu(acc2[1].x * inv + b0.z);
        float v3 = selu(acc2[1].y * inv + b0.w);
        float v4 = selu(acc2[2].x * inv + b1.x);
        float v5 = selu(acc2[2].y * inv + b1.y);
        float v6 = selu(acc2[3].x * inv + b1.z);
        float v7 = selu(acc2[3].y * inv + b1.w);
        uint4 pk;
        pk.x = (unsigned int)f2bf(v0) | ((unsigned int)f2bf(v1) << 16);
        pk.y = (unsigned int)f2bf(v2) | ((unsigned int)f2bf(v3) << 16);
        pk.z = (unsigned int)f2bf(v4) | ((unsigned int)f2bf(v5) << 16);
        pk.w = (unsigned int)f2bf(v6) | ((unsigned int)f2bf(v7) << 16);
        *(uint4*)(out + (size_t)node * HD + c0) = pk;
    }
}

// ---------------- pooling + FC head (fused, one block per graph) ----------------

__device__ __forceinline__ int lower_bound_i(const int* a, int n, int key) {
    int lo = 0, hi = n;
    while (lo < hi) {
        int mid = (lo + hi) >> 1;
        if (a[mid] < key) lo = mid + 1; else hi = mid;
    }
    return lo;
}

__global__ __launch_bounds__(512) void k_poolfc(const unsigned short* __restrict__ x,
                                                const int* __restrict__ batch,
                                                const float* __restrict__ w1,
                                                const float* __restrict__ b1,
                                                const float* __restrict__ w2,
                                                const float* __restrict__ b2,
                                                float* __restrict__ out) {
    int g = blockIdx.x;
    int t = threadIdx.x;
    __shared__ int lo_s, hi_s;
    __shared__ float red[512];
    __shared__ float pooled_s[128];
    if (t == 0) {
        lo_s = lower_bound_i(batch, NN, g);
        hi_s = lower_bound_i(batch, NN, g + 1);
    }
    __syncthreads();
    int lo = lo_s, hi = hi_s;
    float acc = 0.f;
    for (int n = lo + (t >> 7); n < hi; n += 4)
        acc += bf2f(x[(size_t)n * HD + (t & 127)]);
    red[t] = acc;
    __syncthreads();
    if (t < 128) {
        float v = red[t] + red[t + 128] + red[t + 256] + red[t + 384];
        pooled_s[t] = selu(v / fmaxf((float)(hi - lo), 1.f));
    }
    __syncthreads();
    if (t < 64) {
        float z = 0.f;
#pragma unroll 8
        for (int k = 0; k < HD; ++k) z += pooled_s[k] * w1[k * NHID + t];
        z = selu(z + b1[t]);
        float p0 = z * w2[t * NCLS + 0];
        float p1 = z * w2[t * NCLS + 1];
        for (int off = 32; off; off >>= 1) {
            p0 += __shfl_down(p0, off);
            p1 += __shfl_down(p1, off);
        }
        if (t == 0) {
            float l0 = p0 + b2[0], l1 = p1 + b2[1];
            float m = fmaxf(l0, l1);
            float lse = m + __logf(__expf(l0 - m) + __expf(l1 - m));
            out[g * NCLS + 0] = l0 - lse;
            out[g * NCLS + 1] = l1 - lse;
        }
    }
}

// ---------------- launch ----------------

static inline size_t align_up(size_t v, size_t a) { return (v + a - 1) / a * a; }

extern "C" void kernel_launch(void* const* d_in, const int* in_sizes, int n_in,
                              void* d_out, int out_size, void* d_ws, size_t ws_size,
                              hipStream_t stream) {
    const float* x      = (const float*)d_in[0];
    const int*   ei     = (const int*)d_in[1];
    const int*   batch  = (const int*)d_in[2];
    const float* W1     = (const float*)d_in[3];
    const float* a_src1 = (const float*)d_in[4];
    const float* a_dst1 = (const float*)d_in[5];
    const float* b1     = (const float*)d_in[6];
    const float* W2     = (const float*)d_in[7];
    const float* a_src2 = (const float*)d_in[8];
    const float* a_dst2 = (const float*)d_in[9];
    const float* b2     = (const float*)d_in[10];
    const float* fc1_w  = (const float*)d_in[11];
    const float* fc1_b  = (const float*)d_in[12];
    const float* fc2_w  = (const float*)d_in[13];
    const float* fc2_b  = (const float*)d_in[14];
    float* out = (float*)d_out;

    char* ws = (char*)d_ws;
    size_t off = 0;
    unsigned short* h1 = (unsigned short*)(ws + off); off = align_up(off + (size_t)NN * HD * 2, 256);
    unsigned short* o1 = (unsigned short*)(ws + off); off = align_up(off + (size_t)NN * HD * 2, 256);
    float* asrc = (float*)(ws + off); off = align_up(off + (size_t)NN * 4, 256);
    float* adst = (float*)(ws + off); off = align_up(off + (size_t)NN * 4, 256);
    int* cursor = (int*)(ws + off);   off = align_up(off + (size_t)NN * 4, 256);
    int* slots  = (int*)(ws + off);   off = align_up(off + (size_t)NN * SLOTS * 4, 256);
    unsigned short* W1t = (unsigned short*)(ws + off); off = align_up(off + (size_t)HD * KP1 * 2, 256);
    unsigned short* W2t = (unsigned short*)(ws + off); off = align_up(off + (size_t)HD * KP2 * 2, 256);
    (void)ws_size;

    // adjacency build: slotted scatter, XCD-partitioned by dst range
    hipMemsetAsync(cursor, 0, (size_t)NN * 4, stream);
    k_scatter_slots<<<NSLICE * NPART, 256, 0, stream>>>(ei, cursor, slots);

    k_castT2<<<(HD * (KP1 + KP2) + 255) / 256, 256, 0, stream>>>(W1, W2, W1t, W2t);

    int gblocks = (NN + 31) / 32;  // 1563

    // Layer 1
    k_gemm_f32<<<gblocks, 256, 0, stream>>>(x, W1t, h1, asrc, adst, a_src1, a_dst1, NN, FIN, KP1);
    k_gat<<<(NN + 3) / 4, 256, 0, stream>>>(h1, asrc, adst, cursor, slots, b1, o1);

    // Layer 2
    k_gemm_bf16<<<gblocks, 256, 0, stream>>>(o1, W2t, h1, asrc, adst, a_src2, a_dst2, NN, HD, KP2);
    k_gat<<<(NN + 3) / 4, 256, 0, stream>>>(h1, asrc, adst, cursor, slots, b2, o1);

    // Pool + FC head (fused)
    k_poolfc<<<NG, 512, 0, stream>>>(o1, batch, fc1_w, fc1_b, fc2_w, fc2_b, out);
}